// Round 18
// baseline (20098.703 us; speedup 1.0000x reference)
//
#include <hip/hip_runtime.h>
#include <hip/hip_bf16.h>
#include <hip/hip_cooperative_groups.h>

namespace cg = cooperative_groups;

typedef __bf16 bf16;
typedef __bf16 bf16x8 __attribute__((ext_vector_type(8)));
typedef float  f32x4  __attribute__((ext_vector_type(4)));

#define MFMA16(a,b,c) __builtin_amdgcn_mfma_f32_16x16x32_bf16((a),(b),(c),0,0,0)
#define NSTEP 119

// weight frags (bf16 elems); frag (c,kt) = 1024 bf16 [hi512|lo512]
#define O_L0   0u
#define O_L1   491520u
#define O_L2   1277952u
#define O_Z2H  2064384u
#define O_OUTW 2260992u
// fp32 frag arrays (float idx): x [256rt][2kt][512]; h [256rt][8kt][512] x2 parity
#define FXF   1146880u
#define FH0A  1409024u
#define FH1A  3506176u
#define FH2A  5603328u
#define HPAR  1048576u

#define FOFF(m,k) (((k)>>5)*512 + ((m) + 16*(((k)>>3)&3))*8 + ((k)&7))

__device__ __forceinline__ f32x4 splat4(float v){ f32x4 r={v,v,v,v}; return r; }
__device__ __forceinline__ float sigf(float x){ return 1.f/(1.f+expf(-x)); }

// fp32 W[Rt*16][K] -> MFMA B-frags, hi/lo split; frag idx = c*KTg + ktoff + ktm
__global__ void pack2(const float* __restrict__ src, bf16* __restrict__ dst,
                      int Rt, int KTm, int KTg, int ktoff, int K) {
  int idx = blockIdx.x * 256 + threadIdx.x;
  if (idx >= Rt * KTm * 64) return;
  int lane = idx & 63, fi = idx >> 6;
  int r15 = lane & 15, q = lane >> 4;
  int c = fi / KTm, ktm = fi - c * KTm;
  const float* s = src + (size_t)(c * 16 + r15) * K + ktm * 32 + q * 8;
  bf16* d = dst + (size_t)(c * KTg + ktoff + ktm) * 1024 + lane * 8;
  #pragma unroll
  for (int e = 0; e < 8; ++e) {
    float v = s[e];
    bf16 hi = (bf16)v;
    d[e] = hi;
    d[e + 512] = (bf16)(v - (float)hi);
  }
}

// ---- phase bodies (verbatim ports of R17's proven kernels) ----

__device__ void init_phase(const float* __restrict__ z, const float* __restrict__ emb,
                           const float* __restrict__ z2h_b, const bf16* __restrict__ wsb,
                           float* __restrict__ xf, float* __restrict__ h0,
                           float* __restrict__ h1, float* __restrict__ h2,
                           bf16* __restrict__ WSf)
{
  bf16* zF0 = WSf;          // reuse LDS
  bf16* zF1 = WSf + 2048;
  const int tid = threadIdx.x, wv = tid >> 6, lane = tid & 63;
  const int q = lane >> 4, r15 = lane & 15;
  const int rt = blockIdx.x, b0 = rt * 16;
  {
    const int m = tid >> 5, c4 = (tid & 31) * 4;
    float4 v = *(const float4*)(z + (size_t)(b0 + m) * 128 + c4);
    const float vv[4] = {v.x, v.y, v.z, v.w};
    #pragma unroll
    for (int e = 0; e < 4; ++e) {
      int off = FOFF(m, c4 + e);
      bf16 hi = (bf16)vv[e];
      zF0[off] = hi;
      zF1[off] = (bf16)(vv[e] - (float)hi);
    }
  }
  for (int i = tid; i < 1024; i += 512) {
    int m = i >> 6, e = i & 63;
    xf[(size_t)rt * 1024 + FOFF(m, e)] = emb[64 + e];
  }
  __syncthreads();
  f32x4 acc[6];
  #pragma unroll
  for (int t = 0; t < 6; ++t) acc[t] = splat4(z2h_b[(wv * 6 + t) * 16 + r15]);
  #pragma unroll
  for (int kt = 0; kt < 4; ++kt) {
    bf16x8 a0 = *(const bf16x8*)(zF0 + kt * 512 + lane * 8);
    bf16x8 a1 = *(const bf16x8*)(zF1 + kt * 512 + lane * 8);
    #pragma unroll
    for (int t = 0; t < 6; ++t) {
      const bf16* bb = wsb + O_Z2H + (size_t)((wv * 6 + t) * 4 + kt) * 1024 + lane * 8;
      bf16x8 b0 = *(const bf16x8*)bb;
      bf16x8 b1 = *(const bf16x8*)(bb + 512);
      acc[t] = MFMA16(a0, b0, acc[t]);
      acc[t] = MFMA16(a1, b0, acc[t]);
      acc[t] = MFMA16(a0, b1, acc[t]);
    }
  }
  #pragma unroll
  for (int t = 0; t < 6; ++t) {
    const int col = (wv * 6 + t) * 16 + r15;
    const int lay = col >> 8, j = col & 255;
    float* H = lay == 0 ? h0 : lay == 1 ? h1 : h2;
    #pragma unroll
    for (int r = 0; r < 4; ++r)
      H[(size_t)rt * 4096 + FOFF(q * 4 + r, j)] = tanhf(acc[t][r]);
  }
}

template<int L>
__device__ void gate_phase(const float* __restrict__ ain, const float* __restrict__ hin,
                           float* __restrict__ hout,
                           const float* __restrict__ bih, const float* __restrict__ bhh,
                           const bf16* __restrict__ wsb, bf16* __restrict__ WSf)
{
  constexpr int KTI = (L == 0) ? 2 : 8;
  constexpr int KT  = KTI + 8;
  constexpr int PH  = (L == 0) ? 10 : 8;
  constexpr int NPH = (L == 0) ? 1 : 2;
  constexpr int AST = (L == 0) ? 1024 : 4096;
  const size_t WB = (L == 0) ? O_L0 : (L == 1) ? O_L1 : O_L2;

  const int tid = threadIdx.x, wv = tid >> 6, lane = tid & 63;
  const int q = lane >> 4, r15 = lane & 15;
  const int rg = blockIdx.x >> 3, cg = blockIdx.x & 7;
  const int rt = rg * 8 + wv;

  const float* Ain = ain + (size_t)rt * AST;
  const float* Ah  = hin + (size_t)rt * 4096;

  f32x4 accR[2], accZ[2], accNI[2], accNH[2];
  #pragma unroll
  for (int c = 0; c < 2; ++c) {
    accR[c] = splat4(0.f); accZ[c] = splat4(0.f);
    accNI[c] = splat4(0.f); accNH[c] = splat4(0.f);
  }

  #pragma unroll
  for (int p = 0; p < NPH; ++p) {
    const int kb = p * PH;
    for (int u = wv; u < 6 * PH; u += 8) {
      int ct = u % 6, ktp = u / 6;
      int c = (ct >> 1) * 16 + cg * 2 + (ct & 1);
      const bf16* src = wsb + WB + (size_t)(c * KT + kb + ktp) * 1024 + lane * 8;
      bf16x8 t0 = *(const bf16x8*)src;
      bf16x8 t1 = *(const bf16x8*)(src + 512);
      *(bf16x8*)(WSf + (ktp * 6 + ct) * 1024 + lane * 8) = t0;
      *(bf16x8*)(WSf + (ktp * 6 + ct) * 1024 + 512 + lane * 8) = t1;
    }
    __syncthreads();
    const float* ap0 = (kb < KTI) ? (Ain + (size_t)kb * 512 + lane * 8)
                                  : (Ah + (size_t)(kb - KTI) * 512 + lane * 8);
    float4 va = *(const float4*)ap0;
    float4 vb = *(const float4*)(ap0 + 4);
    #pragma unroll
    for (int ktp = 0; ktp < PH; ++ktp) {
      const int kt = kb + ktp;
      float4 na, nb;
      if (ktp + 1 < PH) {
        const int kn = kt + 1;
        const float* apn = (kn < KTI) ? (Ain + (size_t)kn * 512 + lane * 8)
                                      : (Ah + (size_t)(kn - KTI) * 512 + lane * 8);
        na = *(const float4*)apn;
        nb = *(const float4*)(apn + 4);
      }
      const float vv[8] = {va.x, va.y, va.z, va.w, vb.x, vb.y, vb.z, vb.w};
      bf16x8 a0, a1;
      #pragma unroll
      for (int e = 0; e < 8; ++e) {
        bf16 hi = (bf16)vv[e];
        a0[e] = hi;
        a1[e] = (bf16)(vv[e] - (float)hi);
      }
      #pragma unroll
      for (int ct = 0; ct < 6; ++ct) {
        bf16x8 b0 = *(const bf16x8*)(WSf + (ktp * 6 + ct) * 1024 + lane * 8);
        bf16x8 b1 = *(const bf16x8*)(WSf + (ktp * 6 + ct) * 1024 + 512 + lane * 8);
        f32x4* acc;
        const int ctl = ct & 1;
        if (ct < 2)      acc = &accR[ctl];
        else if (ct < 4) acc = &accZ[ctl];
        else             acc = (kt < KTI) ? &accNI[ctl] : &accNH[ctl];
        *acc = MFMA16(a0, b0, *acc);
        *acc = MFMA16(a1, b0, *acc);
        *acc = MFMA16(a0, b1, *acc);
      }
      va = na; vb = nb;
    }
    if (p + 1 < NPH) __syncthreads();
  }

  #pragma unroll
  for (int ctl = 0; ctl < 2; ++ctl) {
    const int j = cg * 32 + ctl * 16 + r15;
    const float brz = bih[j] + bhh[j];
    const float bz  = bih[256 + j] + bhh[256 + j];
    const float bni = bih[512 + j];
    const float bnh = bhh[512 + j];
    #pragma unroll
    for (int r = 0; r < 4; ++r) {
      const int m = q * 4 + r;
      const size_t idx = (size_t)rt * 4096 + FOFF(m, j);
      float rg_ = sigf(accR[ctl][r] + brz);
      float zg  = sigf(accZ[ctl][r] + bz);
      float ng  = tanhf(accNI[ctl][r] + bni + rg_ * (accNH[ctl][r] + bnh));
      float hp  = hin[idx];
      hout[idx] = (1.f - zg) * ng + zg * hp;
    }
  }
}

__device__ void logits_phase(const float* __restrict__ h2, float* __restrict__ xf,
                             const float* __restrict__ emb, const float* __restrict__ out_b,
                             const bf16* __restrict__ wsb, float* __restrict__ out,
                             int step, float (*logS2)[16][68])
{
  const int tid = threadIdx.x, wv = tid >> 6, lane = tid & 63;
  const int q = lane >> 4, r15 = lane & 15;
  const int rt = blockIdx.x;
  const float* A = h2 + (size_t)rt * 4096;

  {
    const int ks = wv >> 2, tt = wv & 3;
    f32x4 acc = ks ? splat4(0.f) : splat4(out_b[tt * 16 + r15]);
    #pragma unroll
    for (int kt2 = 0; kt2 < 4; ++kt2) {
      const int kg = ks * 4 + kt2;
      float4 v0 = *(const float4*)(A + kg * 512 + lane * 8);
      float4 v1 = *(const float4*)(A + kg * 512 + lane * 8 + 4);
      const float vv[8] = {v0.x, v0.y, v0.z, v0.w, v1.x, v1.y, v1.z, v1.w};
      bf16x8 a0, a1;
      #pragma unroll
      for (int e = 0; e < 8; ++e) {
        bf16 hi = (bf16)vv[e];
        a0[e] = hi;
        a1[e] = (bf16)(vv[e] - (float)hi);
      }
      const bf16* bb = wsb + O_OUTW + (size_t)(tt * 8 + kg) * 1024 + lane * 8;
      bf16x8 b0 = *(const bf16x8*)bb;
      bf16x8 b1 = *(const bf16x8*)(bb + 512);
      acc = MFMA16(a0, b0, acc);
      acc = MFMA16(a1, b0, acc);
      acc = MFMA16(a0, b1, acc);
    }
    #pragma unroll
    for (int r = 0; r < 4; ++r)
      logS2[ks][q * 4 + r][tt * 16 + r15] = acc[r];
  }
  __syncthreads();
  #pragma unroll
  for (int k2 = 0; k2 < 2; ++k2) {
    const int rr = wv * 2 + k2;
    float v = logS2[0][rr][lane] + logS2[1][rr][lane];
    out[((size_t)(rt * 16 + rr) * NSTEP + step) * 64 + lane] = v;
    float bv = v; int bi = lane;
    #pragma unroll
    for (int d = 1; d < 64; d <<= 1) {
      float ov = __shfl_xor(bv, d);
      int   oi = __shfl_xor(bi, d);
      if (ov > bv || (ov == bv && oi < bi)) { bv = ov; bi = oi; }
    }
    xf[(size_t)rt * 1024 + FOFF(rr, lane)] = emb[(size_t)bi * 64 + lane];
  }
  __syncthreads();   // logS2 reuse safety before next phase
}

// ---- the single cooperative kernel: init + 119 steps, 4 grid.sync()/step ----
__global__ __launch_bounds__(512, 1)
void moldec_coop(const float* __restrict__ z, const float* __restrict__ emb,
                 const float* __restrict__ z2h_b, const float* __restrict__ out_b,
                 const float* __restrict__ bih0, const float* __restrict__ bhh0,
                 const float* __restrict__ bih1, const float* __restrict__ bhh1,
                 const float* __restrict__ bih2, const float* __restrict__ bhh2,
                 const bf16* __restrict__ wsb, float* __restrict__ wsf,
                 float* __restrict__ out)
{
  __shared__ __align__(16) bf16 WSf[10 * 6 * 1024];   // 120 KB, reused per phase
  __shared__ float logS2[2][16][68];
  cg::grid_group gg = cg::this_grid();

  float* xf = wsf + FXF;

  init_phase(z, emb, z2h_b, wsb, xf,
             wsf + FH0A, wsf + FH1A, wsf + FH2A, WSf);
  gg.sync();

  for (int t = 0; t < NSTEP; ++t) {
    const size_t p = (size_t)(t & 1) * HPAR, pn = (size_t)((t & 1) ^ 1) * HPAR;
    float* h0i = wsf + FH0A + p;  float* h0o = wsf + FH0A + pn;
    float* h1i = wsf + FH1A + p;  float* h1o = wsf + FH1A + pn;
    float* h2i = wsf + FH2A + p;  float* h2o = wsf + FH2A + pn;

    gate_phase<0>(xf,  h0i, h0o, bih0, bhh0, wsb, WSf);
    gg.sync();
    gate_phase<1>(h0o, h1i, h1o, bih1, bhh1, wsb, WSf);
    gg.sync();
    gate_phase<2>(h1o, h2i, h2o, bih2, bhh2, wsb, WSf);
    gg.sync();
    logits_phase(h2o, xf, emb, out_b, wsb, out, t, logS2);
    gg.sync();
  }
}

extern "C" void kernel_launch(void* const* d_in, const int* in_sizes, int n_in,
                              void* d_out, int out_size, void* d_ws, size_t ws_size,
                              hipStream_t stream) {
  bf16*  wsb = (bf16*)d_ws;
  float* wsf = (float*)d_ws;
  const float* z     = (const float*)d_in[0];
  const float* emb   = (const float*)d_in[1];
  const float* z2h_b = (const float*)d_in[3];
  const float* out_b = (const float*)d_in[5];
  const float* bih0 = (const float*)d_in[8],  *bhh0 = (const float*)d_in[9];
  const float* bih1 = (const float*)d_in[12], *bhh1 = (const float*)d_in[13];
  const float* bih2 = (const float*)d_in[16], *bhh2 = (const float*)d_in[17];
  float* out = (float*)d_out;

  pack2<<<24, 256, 0, stream>>>((const float*)d_in[6],  wsb + O_L0,  48, 2, 10, 0, 64);
  pack2<<<96, 256, 0, stream>>>((const float*)d_in[7],  wsb + O_L0,  48, 8, 10, 2, 256);
  pack2<<<96, 256, 0, stream>>>((const float*)d_in[10], wsb + O_L1,  48, 8, 16, 0, 256);
  pack2<<<96, 256, 0, stream>>>((const float*)d_in[11], wsb + O_L1,  48, 8, 16, 8, 256);
  pack2<<<96, 256, 0, stream>>>((const float*)d_in[14], wsb + O_L2,  48, 8, 16, 0, 256);
  pack2<<<96, 256, 0, stream>>>((const float*)d_in[15], wsb + O_L2,  48, 8, 16, 8, 256);
  pack2<<<48, 256, 0, stream>>>((const float*)d_in[2],  wsb + O_Z2H, 48, 4, 4,  0, 128);
  pack2<<<8,  256, 0, stream>>>((const float*)d_in[4],  wsb + O_OUTW, 4, 8, 8,  0, 256);

  void* args[] = {(void*)&z, (void*)&emb, (void*)&z2h_b, (void*)&out_b,
                  (void*)&bih0, (void*)&bhh0, (void*)&bih1, (void*)&bhh1,
                  (void*)&bih2, (void*)&bhh2,
                  (void*)&wsb, (void*)&wsf, (void*)&out};
  hipLaunchCooperativeKernel((void*)moldec_coop, dim3(256), dim3(512),
                             args, 0, stream);
}

// Round 19
// 6289.674 us; speedup vs baseline: 3.1955x; 3.1955x over previous
//
#include <hip/hip_runtime.h>
#include <hip/hip_bf16.h>

typedef __bf16 bf16;
typedef __bf16 bf16x8 __attribute__((ext_vector_type(8)));
typedef float  f32x4  __attribute__((ext_vector_type(4)));

#define MFMA16(a,b,c) __builtin_amdgcn_mfma_f32_16x16x32_bf16((a),(b),(c),0,0,0)
#define NSTEP 119

// weight frags (bf16 elems); frag (c,kt) = 1024 bf16 [hi512|lo512]
#define O_L0   0u
#define O_L1   491520u
#define O_L2   1277952u
#define O_Z2H  2064384u
#define O_OUTW 2260992u
// fp32 h row-major [4096][256] (float idx) + tokens
#define FH0 1146880u
#define FH1 2195456u
#define FH2 3244032u
#define FTOK 4292608u

#define FOFF(m,k) (((k)>>5)*512 + ((m) + 16*(((k)>>3)&3))*8 + ((k)&7))

__device__ __forceinline__ f32x4 splat4(float v){ f32x4 r={v,v,v,v}; return r; }
__device__ __forceinline__ float sigf(float x){ return 1.f/(1.f+expf(-x)); }

// fp32 W[Rt*16][K] -> MFMA B-frags, hi/lo split; frag idx = c*KTg + ktoff + ktm
__global__ void pack2(const float* __restrict__ src, bf16* __restrict__ dst,
                      int Rt, int KTm, int KTg, int ktoff, int K) {
  int idx = blockIdx.x * 256 + threadIdx.x;
  if (idx >= Rt * KTm * 64) return;
  int lane = idx & 63, fi = idx >> 6;
  int r15 = lane & 15, q = lane >> 4;
  int c = fi / KTm, ktm = fi - c * KTm;
  const float* s = src + (size_t)(c * 16 + r15) * K + ktm * 32 + q * 8;
  bf16* d = dst + (size_t)(c * KTg + ktoff + ktm) * 1024 + lane * 8;
  #pragma unroll
  for (int e = 0; e < 8; ++e) {
    float v = s[e];
    bf16 hi = (bf16)v;
    d[e] = hi;
    d[e + 512] = (bf16)(v - (float)hi);
  }
}

// init: h[0..2] = tanh(z @ z2h^T + b) row-major fp32; tokens = 1
__global__ __launch_bounds__(512)
void kinit(const float* __restrict__ z, const float* __restrict__ z2h_b,
           const bf16* __restrict__ wsb, float* __restrict__ wsf,
           int* __restrict__ wsi)
{
  __shared__ __align__(16) bf16 zF[2][2048];
  const int tid = threadIdx.x, wv = tid >> 6, lane = tid & 63;
  const int q = lane >> 4, r15 = lane & 15;
  const int b0 = blockIdx.x * 16;
  {
    const int m = tid >> 5, c4 = (tid & 31) * 4;
    float4 v = *(const float4*)(z + (size_t)(b0 + m) * 128 + c4);
    const float vv[4] = {v.x, v.y, v.z, v.w};
    #pragma unroll
    for (int e = 0; e < 4; ++e) {
      int off = FOFF(m, c4 + e);
      bf16 hi = (bf16)vv[e];
      zF[0][off] = hi;
      zF[1][off] = (bf16)(vv[e] - (float)hi);
    }
    if (tid < 16) wsi[FTOK + b0 + tid] = 1;
  }
  __syncthreads();
  f32x4 acc[6];
  #pragma unroll
  for (int t = 0; t < 6; ++t) acc[t] = splat4(z2h_b[(wv * 6 + t) * 16 + r15]);
  #pragma unroll
  for (int kt = 0; kt < 4; ++kt) {
    bf16x8 a0 = *(const bf16x8*)(&zF[0][kt * 512 + lane * 8]);
    bf16x8 a1 = *(const bf16x8*)(&zF[1][kt * 512 + lane * 8]);
    #pragma unroll
    for (int t = 0; t < 6; ++t) {
      const bf16* bb = wsb + O_Z2H + (size_t)((wv * 6 + t) * 4 + kt) * 1024 + lane * 8;
      bf16x8 b0 = *(const bf16x8*)bb;
      bf16x8 b1 = *(const bf16x8*)(bb + 512);
      acc[t] = MFMA16(a0, b0, acc[t]);
      acc[t] = MFMA16(a1, b0, acc[t]);
      acc[t] = MFMA16(a0, b1, acc[t]);
    }
  }
  #pragma unroll
  for (int t = 0; t < 6; ++t) {
    const int col = (wv * 6 + t) * 16 + r15;
    const int lay = col >> 8, j = col & 255;
    float* H = wsf + (lay == 0 ? FH0 : lay == 1 ? FH1 : FH2);
    #pragma unroll
    for (int r = 0; r < 4; ++r)
      H[(size_t)(b0 + q * 4 + r) * 256 + j] = tanhf(acc[t][r]);
  }
}

__device__ __forceinline__ void gl16(bf16x8& d, const bf16* p) {
  asm volatile("global_load_dwordx4 %0, %1, off" : "=v"(d) : "v"(p));
}

// One fused gate layer: GEMM (asm ring-2, counted vmcnt) + GRU update.
// Ain/Ah are LDS frag buffers; out: fp32 global h + bf16 frag buffer Bout.
template<int KTI>
__device__ __forceinline__ void gate_layer(
    const bf16* __restrict__ Ain0, const bf16* __restrict__ Ain1,
    const bf16* __restrict__ Ah0,  const bf16* __restrict__ Ah1,
    bf16* __restrict__ Bout0, bf16* __restrict__ Bout1,
    const float* __restrict__ bih, const float* __restrict__ bhh,
    const bf16* __restrict__ Wbase, float* __restrict__ Hg,
    const int b0, const int wv, const int lane)
{
  constexpr int KT = KTI + 8;
  const int q = lane >> 4, r15 = lane & 15;

  f32x4 aR[2], aZ[2], aNI[2], aNH[2];
  #pragma unroll
  for (int jt = 0; jt < 2; ++jt) {
    aR[jt] = splat4(0.f); aZ[jt] = splat4(0.f);
    aNI[jt] = splat4(0.f); aNH[jt] = splat4(0.f);
  }
  const bf16* bp[6];
  #pragma unroll
  for (int g3 = 0; g3 < 3; ++g3)
    #pragma unroll
    for (int jt = 0; jt < 2; ++jt)
      bp[g3 * 2 + jt] = Wbase + (size_t)((g3 * 16 + wv * 2 + jt) * KT) * 1024 + lane * 8;

  bf16x8 rb[2][6][2];
  asm volatile("s_waitcnt vmcnt(0)" ::: "memory");
  __builtin_amdgcn_sched_barrier(0);
  #pragma unroll
  for (int t = 0; t < 6; ++t) {
    gl16(rb[0][t][0], bp[t]);
    gl16(rb[0][t][1], bp[t] + 512);
  }
  #pragma unroll
  for (int kt = 0; kt < KT; ++kt) {
    const int s = kt & 1;
    if (kt + 1 < KT) {
      #pragma unroll
      for (int t = 0; t < 6; ++t) {
        gl16(rb[s ^ 1][t][0], bp[t] + (size_t)(kt + 1) * 1024);
        gl16(rb[s ^ 1][t][1], bp[t] + (size_t)(kt + 1) * 1024 + 512);
      }
      asm volatile("s_waitcnt vmcnt(12)" ::: "memory");
    } else {
      asm volatile("s_waitcnt vmcnt(0)" ::: "memory");
    }
    __builtin_amdgcn_sched_barrier(0);
    const bf16* A0;
    const bf16* A1;
    if (kt < KTI) { A0 = Ain0 + kt * 512; A1 = Ain1 + kt * 512; }
    else          { A0 = Ah0 + (kt - KTI) * 512; A1 = Ah1 + (kt - KTI) * 512; }
    bf16x8 a0 = *(const bf16x8*)(A0 + lane * 8);
    bf16x8 a1 = *(const bf16x8*)(A1 + lane * 8);
    #pragma unroll
    for (int jt = 0; jt < 2; ++jt) {
      aR[jt] = MFMA16(a0, rb[s][jt][0], aR[jt]);
      aR[jt] = MFMA16(a1, rb[s][jt][0], aR[jt]);
      aR[jt] = MFMA16(a0, rb[s][jt][1], aR[jt]);
      aZ[jt] = MFMA16(a0, rb[s][2 + jt][0], aZ[jt]);
      aZ[jt] = MFMA16(a1, rb[s][2 + jt][0], aZ[jt]);
      aZ[jt] = MFMA16(a0, rb[s][2 + jt][1], aZ[jt]);
      f32x4& aN = (kt < KTI) ? aNI[jt] : aNH[jt];
      aN = MFMA16(a0, rb[s][4 + jt][0], aN);
      aN = MFMA16(a1, rb[s][4 + jt][0], aN);
      aN = MFMA16(a0, rb[s][4 + jt][1], aN);
    }
  }

  // GRU update: fp32 global h (read-then-write, block-local) + frag handoff
  #pragma unroll
  for (int jt = 0; jt < 2; ++jt) {
    const int j = wv * 32 + jt * 16 + r15;
    const float brz = bih[j] + bhh[j];
    const float bz  = bih[256 + j] + bhh[256 + j];
    const float bni = bih[512 + j];
    const float bnh = bhh[512 + j];
    #pragma unroll
    for (int r = 0; r < 4; ++r) {
      const int m = q * 4 + r;
      float rg = sigf(aR[jt][r] + brz);
      float zg = sigf(aZ[jt][r] + bz);
      float ng = tanhf(aNI[jt][r] + bni + rg * (aNH[jt][r] + bnh));
      float hp = Hg[(size_t)(b0 + m) * 256 + j];
      float hv = (1.f - zg) * ng + zg * hp;
      Hg[(size_t)(b0 + m) * 256 + j] = hv;
      const int off = FOFF(m, j);
      bf16 hi = (bf16)hv;
      Bout0[off] = hi;
      Bout1[off] = (bf16)(hv - (float)hi);
    }
  }
}

__device__ __forceinline__ void stage_h(bf16* __restrict__ B0, bf16* __restrict__ B1,
                                        const float* __restrict__ Hg, const int b0,
                                        const int tid)
{
  const int m = tid >> 5, c8 = (tid & 31) * 8;
  float4 v0 = *(const float4*)(Hg + (size_t)(b0 + m) * 256 + c8);
  float4 v1 = *(const float4*)(Hg + (size_t)(b0 + m) * 256 + c8 + 4);
  const float vv[8] = {v0.x, v0.y, v0.z, v0.w, v1.x, v1.y, v1.z, v1.w};
  #pragma unroll
  for (int e = 0; e < 8; ++e) {
    int off = FOFF(m, c8 + e);
    bf16 hi = (bf16)vv[e];
    B0[off] = hi;
    B1[off] = (bf16)(vv[e] - (float)hi);
  }
}

// One full GRU step for 16 batch rows: L0+L1+L2+logits+argmax, block-local.
__global__ __launch_bounds__(512)
void kstep(const float* __restrict__ emb,
           const float* __restrict__ bih0, const float* __restrict__ bhh0,
           const float* __restrict__ bih1, const float* __restrict__ bhh1,
           const float* __restrict__ bih2, const float* __restrict__ bhh2,
           const float* __restrict__ out_b,
           const bf16* __restrict__ wsb, float* __restrict__ wsf,
           int* __restrict__ wsi, float* __restrict__ out, int step)
{
  __shared__ __align__(16) bf16 BxA[2][1024];   // x frags (2 kt)
  __shared__ __align__(16) bf16 Bh[2][4096];    // current-layer h frags (restaged)
  __shared__ __align__(16) bf16 Bo0[2][4096];   // L0 out / L2 out (reused)
  __shared__ __align__(16) bf16 Bo1[2][4096];   // L1 out
  __shared__ float logS2[2][16][68];

  const int tid = threadIdx.x, wv = tid >> 6, lane = tid & 63;
  const int q = lane >> 4, r15 = lane & 15;
  const int b0 = blockIdx.x * 16;

  // ---- stage x = emb[token] and h0 frags ----
  if (tid < 256) {
    const int m = tid >> 4, e4 = (tid & 15) * 4;
    const int tk = wsi[FTOK + b0 + m];
    float4 v = *(const float4*)(emb + (size_t)tk * 64 + e4);
    const float vv[4] = {v.x, v.y, v.z, v.w};
    #pragma unroll
    for (int e = 0; e < 4; ++e) {
      int off = FOFF(m, e4 + e);
      bf16 hi = (bf16)vv[e];
      BxA[0][off] = hi;
      BxA[1][off] = (bf16)(vv[e] - (float)hi);
    }
  }
  stage_h(Bh[0], Bh[1], wsf + FH0, b0, tid);
  __syncthreads();

  // ---- L0 ----
  gate_layer<2>(BxA[0], BxA[1], Bh[0], Bh[1], Bo0[0], Bo0[1],
                bih0, bhh0, wsb + O_L0, wsf + FH0, b0, wv, lane);
  __syncthreads();
  stage_h(Bh[0], Bh[1], wsf + FH1, b0, tid);
  __syncthreads();

  // ---- L1 ----
  gate_layer<8>(Bo0[0], Bo0[1], Bh[0], Bh[1], Bo1[0], Bo1[1],
                bih1, bhh1, wsb + O_L1, wsf + FH1, b0, wv, lane);
  __syncthreads();
  stage_h(Bh[0], Bh[1], wsf + FH2, b0, tid);
  __syncthreads();

  // ---- L2 ----
  gate_layer<8>(Bo1[0], Bo1[1], Bh[0], Bh[1], Bo0[0], Bo0[1],
                bih2, bhh2, wsb + O_L2, wsf + FH2, b0, wv, lane);
  __syncthreads();

  // ---- logits from Bo0 (h2' frags) ----
  {
    const int ks = wv >> 2, tt = wv & 3;
    f32x4 acc = ks ? splat4(0.f) : splat4(out_b[tt * 16 + r15]);
    #pragma unroll
    for (int kt2 = 0; kt2 < 4; ++kt2) {
      const int kg = ks * 4 + kt2;
      bf16x8 a0 = *(const bf16x8*)(&Bo0[0][kg * 512 + lane * 8]);
      bf16x8 a1 = *(const bf16x8*)(&Bo0[1][kg * 512 + lane * 8]);
      const bf16* bb = wsb + O_OUTW + (size_t)(tt * 8 + kg) * 1024 + lane * 8;
      bf16x8 b0 = *(const bf16x8*)bb;
      bf16x8 b1 = *(const bf16x8*)(bb + 512);
      acc = MFMA16(a0, b0, acc);
      acc = MFMA16(a1, b0, acc);
      acc = MFMA16(a0, b1, acc);
    }
    #pragma unroll
    for (int r = 0; r < 4; ++r)
      logS2[ks][q * 4 + r][tt * 16 + r15] = acc[r];
  }
  __syncthreads();
  #pragma unroll
  for (int k2 = 0; k2 < 2; ++k2) {
    const int rr = wv * 2 + k2;
    float v = logS2[0][rr][lane] + logS2[1][rr][lane];
    out[((size_t)(b0 + rr) * NSTEP + step) * 64 + lane] = v;
    float bv = v; int bi = lane;
    #pragma unroll
    for (int d = 1; d < 64; d <<= 1) {
      float ov = __shfl_xor(bv, d);
      int   oi = __shfl_xor(bi, d);
      if (ov > bv || (ov == bv && oi < bi)) { bv = ov; bi = oi; }
    }
    if (lane == 0) wsi[FTOK + b0 + rr] = bi;
  }
}

extern "C" void kernel_launch(void* const* d_in, const int* in_sizes, int n_in,
                              void* d_out, int out_size, void* d_ws, size_t ws_size,
                              hipStream_t stream) {
  bf16*  wsb = (bf16*)d_ws;
  float* wsf = (float*)d_ws;
  int*   wsi = (int*)d_ws;
  const float* z     = (const float*)d_in[0];
  const float* emb   = (const float*)d_in[1];
  const float* z2h_b = (const float*)d_in[3];
  const float* out_b = (const float*)d_in[5];
  const float* bih0 = (const float*)d_in[8],  *bhh0 = (const float*)d_in[9];
  const float* bih1 = (const float*)d_in[12], *bhh1 = (const float*)d_in[13];
  const float* bih2 = (const float*)d_in[16], *bhh2 = (const float*)d_in[17];
  float* out = (float*)d_out;

  pack2<<<24, 256, 0, stream>>>((const float*)d_in[6],  wsb + O_L0,  48, 2, 10, 0, 64);
  pack2<<<96, 256, 0, stream>>>((const float*)d_in[7],  wsb + O_L0,  48, 8, 10, 2, 256);
  pack2<<<96, 256, 0, stream>>>((const float*)d_in[10], wsb + O_L1,  48, 8, 16, 0, 256);
  pack2<<<96, 256, 0, stream>>>((const float*)d_in[11], wsb + O_L1,  48, 8, 16, 8, 256);
  pack2<<<96, 256, 0, stream>>>((const float*)d_in[14], wsb + O_L2,  48, 8, 16, 0, 256);
  pack2<<<96, 256, 0, stream>>>((const float*)d_in[15], wsb + O_L2,  48, 8, 16, 8, 256);
  pack2<<<48, 256, 0, stream>>>((const float*)d_in[2],  wsb + O_Z2H, 48, 4, 4,  0, 128);
  pack2<<<8,  256, 0, stream>>>((const float*)d_in[4],  wsb + O_OUTW, 4, 8, 8,  0, 256);

  kinit<<<256, 512, 0, stream>>>(z, z2h_b, wsb, wsf, wsi);

  for (int t = 0; t < NSTEP; ++t)
    kstep<<<256, 512, 0, stream>>>(emb, bih0, bhh0, bih1, bhh1, bih2, bhh2,
                                   out_b, wsb, wsf, wsi, out, t);
}